// Round 1
// baseline (1553.974 us; speedup 1.0000x reference)
//
#include <hip/hip_runtime.h>
#include <math.h>

#define NSRC 50000
#define NTGT 50000
#define NTOT 100000
#define NEDGE 800000
#define DIM 128
#define KC 64  // k-chunk for GEMM LDS staging

// ---------------- degree / norm ----------------

__global__ void k_deg_init(int* __restrict__ deg) {
    int i = blockIdx.x * blockDim.x + threadIdx.x;
    if (i < NTOT) deg[i] = 1;  // self-loop
}

__global__ void k_deg_count(const int* __restrict__ col, int* __restrict__ deg) {
    int e = blockIdx.x * blockDim.x + threadIdx.x;
    if (e < NEDGE) atomicAdd(&deg[col[e] + NSRC], 1);
}

// converts deg (int) -> dinv (float) in place (same memory, per-thread RMW)
__global__ void k_dinv(int* __restrict__ degmem) {
    int i = blockIdx.x * blockDim.x + threadIdx.x;
    if (i < NTOT) {
        int d = degmem[i];
        float f = rsqrtf((float)d);
        ((float*)degmem)[i] = f;
    }
}

// ---------------- h = x @ W ----------------
// block = 256 threads: n4 = tid&31 -> 4 output cols (4*n4..4*n4+3),
// rg = tid>>5 -> 4 rows (rg*4..rg*4+3). 32 rows per block, grid = NTOT/32.
__global__ __launch_bounds__(256) void k_gemm(const float* __restrict__ xsrc,
                                              const float* __restrict__ xtgt,
                                              const float* __restrict__ W,
                                              float* __restrict__ h) {
    __shared__ float4 Wl[KC * 32];        // [KC][128] floats
    __shared__ float4 Xl[32 * (KC / 4)];  // [32 rows][KC] floats

    const int tid = threadIdx.x;
    const int n4 = tid & 31;
    const int rg = tid >> 5;
    const int base = blockIdx.x * 32;

    float4 acc[4];
#pragma unroll
    for (int rr = 0; rr < 4; ++rr) acc[rr] = make_float4(0.f, 0.f, 0.f, 0.f);

    for (int c = 0; c < DIM / KC; ++c) {
        __syncthreads();
        // stage W chunk: k rows c*KC .. c*KC+KC-1, all 128 cols
        for (int idx = tid; idx < KC * 32; idx += 256) {
            int k = idx >> 5, nn = idx & 31;
            Wl[idx] = ((const float4*)(W + (size_t)(c * KC + k) * DIM))[nn];
        }
        // stage x chunk: 32 rows x KC cols
        for (int idx = tid; idx < 32 * (KC / 4); idx += 256) {
            int r = idx / (KC / 4), cc = idx % (KC / 4);
            int g = base + r;
            const float* src = (g < NSRC) ? (xsrc + (size_t)g * DIM)
                                          : (xtgt + (size_t)(g - NSRC) * DIM);
            Xl[idx] = ((const float4*)(src + c * KC))[cc];
        }
        __syncthreads();

#pragma unroll 4
        for (int k4 = 0; k4 < KC / 4; ++k4) {
            float4 xv[4];
#pragma unroll
            for (int rr = 0; rr < 4; ++rr)
                xv[rr] = Xl[(rg * 4 + rr) * (KC / 4) + k4];
#pragma unroll
            for (int kk = 0; kk < 4; ++kk) {
                float4 wv = Wl[(k4 * 4 + kk) * 32 + n4];
#pragma unroll
                for (int rr = 0; rr < 4; ++rr) {
                    float s = (kk == 0) ? xv[rr].x : (kk == 1) ? xv[rr].y
                              : (kk == 2) ? xv[rr].z : xv[rr].w;
                    acc[rr].x += s * wv.x;
                    acc[rr].y += s * wv.y;
                    acc[rr].z += s * wv.z;
                    acc[rr].w += s * wv.w;
                }
            }
        }
    }

#pragma unroll
    for (int rr = 0; rr < 4; ++rr) {
        int g = base + rg * 4 + rr;
        ((float4*)h)[(size_t)g * 32 + n4] = acc[rr];
    }
}

// ---------------- out init with self-loop contribution ----------------
__global__ void k_selfinit(const float* __restrict__ h,
                           const float* __restrict__ dinv,
                           float* __restrict__ out) {
    size_t gid = (size_t)blockIdx.x * blockDim.x + threadIdx.x;  // float4 idx
    if (gid < (size_t)NTOT * 32) {
        int node = (int)(gid >> 5);
        float di = dinv[node];
        float s = di * di;
        float4 v = ((const float4*)h)[gid];
        float4 o;
        o.x = v.x * s; o.y = v.y * s; o.z = v.z * s; o.w = v.w * s;
        ((float4*)out)[gid] = o;
    }
}

// ---------------- edge scatter-add ----------------
// 32 lanes per edge, 8 edges per 256-thread block
__global__ __launch_bounds__(256) void k_scatter(const int* __restrict__ row,
                                                 const int* __restrict__ col,
                                                 const float* __restrict__ h,
                                                 const float* __restrict__ dinv,
                                                 float* out) {
    int e = blockIdx.x * 8 + (threadIdx.x >> 5);
    int lane = threadIdx.x & 31;
    if (e < NEDGE) {
        int r = row[e];
        int c = col[e] + NSRC;
        float nrm = dinv[r] * dinv[c];
        float4 v = ((const float4*)h)[(size_t)r * 32 + lane];
        float* o = out + (size_t)c * DIM + lane * 4;
        atomicAdd(o + 0, v.x * nrm);
        atomicAdd(o + 1, v.y * nrm);
        atomicAdd(o + 2, v.z * nrm);
        atomicAdd(o + 3, v.w * nrm);
    }
}

// ---------------- relu ----------------
__global__ void k_relu(float* __restrict__ out) {
    size_t gid = (size_t)blockIdx.x * blockDim.x + threadIdx.x;  // float4 idx
    if (gid < (size_t)NTOT * 32) {
        float4 v = ((float4*)out)[gid];
        v.x = fmaxf(v.x, 0.f); v.y = fmaxf(v.y, 0.f);
        v.z = fmaxf(v.z, 0.f); v.w = fmaxf(v.w, 0.f);
        ((float4*)out)[gid] = v;
    }
}

extern "C" void kernel_launch(void* const* d_in, const int* in_sizes, int n_in,
                              void* d_out, int out_size, void* d_ws, size_t ws_size,
                              hipStream_t stream) {
    const int* ei    = (const int*)d_in[0];     // [2, E] int32
    const float* xsrc = (const float*)d_in[1];  // [NSRC, 128]
    const float* xtgt = (const float*)d_in[2];  // [NTGT, 128]
    const float* W    = (const float*)d_in[3];  // [128, 128]
    float* out = (float*)d_out;                 // [NTOT, 128]

    float* h  = (float*)d_ws;                                          // 51.2 MB
    int* deg  = (int*)((char*)d_ws + (size_t)NTOT * DIM * sizeof(float));  // 400 KB

    const int* row = ei;
    const int* col = ei + NEDGE;

    k_deg_init<<<(NTOT + 255) / 256, 256, 0, stream>>>(deg);
    k_deg_count<<<(NEDGE + 255) / 256, 256, 0, stream>>>(col, deg);
    k_dinv<<<(NTOT + 255) / 256, 256, 0, stream>>>(deg);
    k_gemm<<<NTOT / 32, 256, 0, stream>>>(xsrc, xtgt, W, h);
    k_selfinit<<<(NTOT * 32 + 255) / 256, 256, 0, stream>>>(
        h, (const float*)deg, out);
    k_scatter<<<(NEDGE + 7) / 8, 256, 0, stream>>>(
        row, col, h, (const float*)deg, out);
    k_relu<<<(NTOT * 32 + 255) / 256, 256, 0, stream>>>(out);
}

// Round 2
// 296.331 us; speedup vs baseline: 5.2440x; 5.2440x over previous
//
#include <hip/hip_runtime.h>
#include <math.h>

#define NSRC 50000
#define NTGT 50000
#define NTOT 100000
#define NEDGE 800000
#define DIM 128
#define KC 64           // k-chunk for GEMM LDS staging
#define SCAN_BLK 512    // elements per scan block
#define SCAN_NB 98      // ceil(50000/512)

// ---------------- zero counters ----------------
__global__ void k_zero(int* __restrict__ p, int n) {
    int i = blockIdx.x * blockDim.x + threadIdx.x;
    if (i < n) p[i] = 0;
}

// ---------------- histogram of targets ----------------
__global__ void k_hist(const int* __restrict__ col, int* __restrict__ cnt) {
    int e = blockIdx.x * blockDim.x + threadIdx.x;
    if (e < NEDGE) atomicAdd(&cnt[col[e]], 1);
}

// ---------------- 3-kernel exclusive scan over cnt[NTGT] ----------------
__global__ __launch_bounds__(SCAN_BLK) void k_scan_block(const int* __restrict__ cnt,
                                                         int* __restrict__ off,
                                                         int* __restrict__ bsum) {
    __shared__ int A[SCAN_BLK], B[SCAN_BLK];
    int tid = threadIdx.x;
    int i = blockIdx.x * SCAN_BLK + tid;
    int v = (i < NTGT) ? cnt[i] : 0;
    A[tid] = v;
    int* src = A; int* dst = B;
    for (int d = 1; d < SCAN_BLK; d <<= 1) {
        __syncthreads();
        dst[tid] = src[tid] + ((tid >= d) ? src[tid - d] : 0);
        int* t = src; src = dst; dst = t;
    }
    __syncthreads();
    if (i < NTGT) off[i] = src[tid] - v;  // exclusive
    if (tid == SCAN_BLK - 1) bsum[blockIdx.x] = src[tid];
}

__global__ __launch_bounds__(128) void k_scan_top(int* __restrict__ bsum,
                                                  int* __restrict__ bscan) {
    __shared__ int A[128], B[128];
    int tid = threadIdx.x;
    int v = (tid < SCAN_NB) ? bsum[tid] : 0;
    A[tid] = v;
    int* src = A; int* dst = B;
    for (int d = 1; d < 128; d <<= 1) {
        __syncthreads();
        dst[tid] = src[tid] + ((tid >= d) ? src[tid - d] : 0);
        int* t = src; src = dst; dst = t;
    }
    __syncthreads();
    if (tid < SCAN_NB) bscan[tid] = src[tid] - v;
}

__global__ void k_scan_add(int* __restrict__ off, const int* __restrict__ bscan) {
    int i = blockIdx.x * blockDim.x + threadIdx.x;
    if (i < NTGT) off[i] += bscan[i >> 9];
}

// ---------------- bucket edges by target ----------------
__global__ void k_build(const int* __restrict__ row, const int* __restrict__ col,
                        const int* __restrict__ off, int* __restrict__ cursor,
                        int* __restrict__ csr) {
    int e = blockIdx.x * blockDim.x + threadIdx.x;
    if (e < NEDGE) {
        int c = col[e];
        int pos = off[c] + atomicAdd(&cursor[c], 1);
        csr[pos] = row[e];
    }
}

// ---------------- h = x @ W (fp32, LDS-tiled); fused out_s = relu(h_s) ----
__global__ __launch_bounds__(256) void k_gemm(const float* __restrict__ xsrc,
                                              const float* __restrict__ xtgt,
                                              const float* __restrict__ W,
                                              float* __restrict__ h,
                                              float* __restrict__ out) {
    __shared__ float4 Wl[KC * 32];        // [KC][128] floats
    __shared__ float4 Xl[32 * (KC / 4)];  // [32 rows][KC] floats

    const int tid = threadIdx.x;
    const int n4 = tid & 31;
    const int rg = tid >> 5;
    const int base = blockIdx.x * 32;

    float4 acc[4];
#pragma unroll
    for (int rr = 0; rr < 4; ++rr) acc[rr] = make_float4(0.f, 0.f, 0.f, 0.f);

    for (int c = 0; c < DIM / KC; ++c) {
        __syncthreads();
        for (int idx = tid; idx < KC * 32; idx += 256) {
            int k = idx >> 5, nn = idx & 31;
            Wl[idx] = ((const float4*)(W + (size_t)(c * KC + k) * DIM))[nn];
        }
        for (int idx = tid; idx < 32 * (KC / 4); idx += 256) {
            int r = idx / (KC / 4), cc = idx % (KC / 4);
            int g = base + r;
            const float* src = (g < NSRC) ? (xsrc + (size_t)g * DIM)
                                          : (xtgt + (size_t)(g - NSRC) * DIM);
            Xl[idx] = ((const float4*)(src + c * KC))[cc];
        }
        __syncthreads();

#pragma unroll 4
        for (int k4 = 0; k4 < KC / 4; ++k4) {
            float4 xv[4];
#pragma unroll
            for (int rr = 0; rr < 4; ++rr)
                xv[rr] = Xl[(rg * 4 + rr) * (KC / 4) + k4];
#pragma unroll
            for (int kk = 0; kk < 4; ++kk) {
                float4 wv = Wl[(k4 * 4 + kk) * 32 + n4];
#pragma unroll
                for (int rr = 0; rr < 4; ++rr) {
                    float s = (kk == 0) ? xv[rr].x : (kk == 1) ? xv[rr].y
                              : (kk == 2) ? xv[rr].z : xv[rr].w;
                    acc[rr].x += s * wv.x;
                    acc[rr].y += s * wv.y;
                    acc[rr].z += s * wv.z;
                    acc[rr].w += s * wv.w;
                }
            }
        }
    }

#pragma unroll
    for (int rr = 0; rr < 4; ++rr) {
        int g = base + rg * 4 + rr;
        ((float4*)h)[(size_t)g * 32 + n4] = acc[rr];
        if (g < NSRC) {  // source nodes: deg=1, dinv=1 -> out = relu(h)
            float4 o = acc[rr];
            o.x = fmaxf(o.x, 0.f); o.y = fmaxf(o.y, 0.f);
            o.z = fmaxf(o.z, 0.f); o.w = fmaxf(o.w, 0.f);
            ((float4*)out)[(size_t)g * 32 + n4] = o;
        }
    }
}

// ---------------- per-target gather-reduce ----------------
// one wave (64 lanes) per target, float2 per lane; 4 targets / 256-thr block
__global__ __launch_bounds__(256) void k_agg(const int* __restrict__ off,
                                             const int* __restrict__ cnt,
                                             const int* __restrict__ csr,
                                             const float* __restrict__ h,
                                             float* __restrict__ out) {
    int w = threadIdx.x >> 6;
    int lane = threadIdx.x & 63;
    int c = blockIdx.x * 4 + w;
    if (c >= NTGT) return;

    int s0 = off[c];
    int n = cnt[c];
    const float2* h2 = (const float2*)h;

    float2 sum = make_float2(0.f, 0.f);
    int j = 0;
    while (j < n) {
        int nb = (n - j < 64) ? (n - j) : 64;
        int v = (lane < nb) ? csr[s0 + j + lane] : 0;
#pragma unroll 4
        for (int k = 0; k < nb; ++k) {
            int r = __shfl(v, k, 64);
            float2 hv = h2[(size_t)r * 64 + lane];
            sum.x += hv.x;
            sum.y += hv.y;
        }
        j += nb;
    }

    float di = rsqrtf(1.0f + (float)n);
    float2 hv = h2[(size_t)(NSRC + c) * 64 + lane];
    float2 o;
    o.x = fmaxf(di * sum.x + di * di * hv.x, 0.f);
    o.y = fmaxf(di * sum.y + di * di * hv.y, 0.f);
    ((float2*)out)[(size_t)(NSRC + c) * 64 + lane] = o;
}

extern "C" void kernel_launch(void* const* d_in, const int* in_sizes, int n_in,
                              void* d_out, int out_size, void* d_ws, size_t ws_size,
                              hipStream_t stream) {
    const int* ei     = (const int*)d_in[0];    // [2, E] int32
    const float* xsrc = (const float*)d_in[1];  // [NSRC, 128]
    const float* xtgt = (const float*)d_in[2];  // [NTGT, 128]
    const float* W    = (const float*)d_in[3];  // [128, 128]
    float* out = (float*)d_out;                 // [NTOT, 128]

    const int* row = ei;
    const int* col = ei + NEDGE;

    char* ws = (char*)d_ws;
    float* h    = (float*)ws;                       ws += (size_t)NTOT * DIM * 4;  // 51.2 MB
    int* cnt    = (int*)ws;                         ws += NTGT * 4;
    int* cursor = (int*)ws;                         ws += NTGT * 4;
    int* off    = (int*)ws;                         ws += NTGT * 4;
    int* bsum   = (int*)ws;                         ws += 512;
    int* bscan  = (int*)ws;                         ws += 512;
    int* csr    = (int*)ws;                         ws += (size_t)NEDGE * 4;       // 3.2 MB

    k_zero<<<(2 * NTGT + 255) / 256, 256, 0, stream>>>(cnt, 2 * NTGT);  // cnt+cursor adjacent
    k_hist<<<(NEDGE + 255) / 256, 256, 0, stream>>>(col, cnt);
    k_scan_block<<<SCAN_NB, SCAN_BLK, 0, stream>>>(cnt, off, bsum);
    k_scan_top<<<1, 128, 0, stream>>>(bsum, bscan);
    k_scan_add<<<(NTGT + 255) / 256, 256, 0, stream>>>(off, bscan);
    k_build<<<(NEDGE + 255) / 256, 256, 0, stream>>>(row, col, off, cursor, csr);
    k_gemm<<<NTOT / 32, 256, 0, stream>>>(xsrc, xtgt, W, h, out);
    k_agg<<<(NTGT + 3) / 4, 256, 0, stream>>>(off, cnt, csr, h, out);
}

// Round 3
// 260.128 us; speedup vs baseline: 5.9739x; 1.1392x over previous
//
#include <hip/hip_runtime.h>
#include <math.h>

#define NSRC 50000
#define NTGT 50000
#define NTOT 100000
#define NEDGE 800000
#define DIM 128
#define SCAN_BLK 512    // elements per scan block
#define SCAN_NB 98      // ceil(50000/512)

typedef __attribute__((ext_vector_type(8))) short short8;
typedef __attribute__((ext_vector_type(4))) float float4v;

__device__ __forceinline__ unsigned short f2bf(float f) {
    unsigned u = __float_as_uint(f);
    unsigned r = (u + 0x7FFFu + ((u >> 16) & 1u)) >> 16;  // RNE
    return (unsigned short)r;
}
__device__ __forceinline__ float bf2f(unsigned us) {
    return __uint_as_float(us << 16);
}

// ---------------- zero counters ----------------
__global__ void k_zero(int* __restrict__ p, int n) {
    int i = blockIdx.x * blockDim.x + threadIdx.x;
    if (i < n) p[i] = 0;
}

// ---------------- histogram of targets ----------------
__global__ void k_hist(const int* __restrict__ col, int* __restrict__ cnt) {
    int e = blockIdx.x * blockDim.x + threadIdx.x;
    if (e < NEDGE) atomicAdd(&cnt[col[e]], 1);
}

// ---------------- 3-kernel exclusive scan over cnt[NTGT] ----------------
__global__ __launch_bounds__(SCAN_BLK) void k_scan_block(const int* __restrict__ cnt,
                                                         int* __restrict__ off,
                                                         int* __restrict__ bsum) {
    __shared__ int A[SCAN_BLK], B[SCAN_BLK];
    int tid = threadIdx.x;
    int i = blockIdx.x * SCAN_BLK + tid;
    int v = (i < NTGT) ? cnt[i] : 0;
    A[tid] = v;
    int* src = A; int* dst = B;
    for (int d = 1; d < SCAN_BLK; d <<= 1) {
        __syncthreads();
        dst[tid] = src[tid] + ((tid >= d) ? src[tid - d] : 0);
        int* t = src; src = dst; dst = t;
    }
    __syncthreads();
    if (i < NTGT) off[i] = src[tid] - v;  // exclusive
    if (tid == SCAN_BLK - 1) bsum[blockIdx.x] = src[tid];
}

__global__ __launch_bounds__(128) void k_scan_top(int* __restrict__ bsum,
                                                  int* __restrict__ bscan) {
    __shared__ int A[128], B[128];
    int tid = threadIdx.x;
    int v = (tid < SCAN_NB) ? bsum[tid] : 0;
    A[tid] = v;
    int* src = A; int* dst = B;
    for (int d = 1; d < 128; d <<= 1) {
        __syncthreads();
        dst[tid] = src[tid] + ((tid >= d) ? src[tid - d] : 0);
        int* t = src; src = dst; dst = t;
    }
    __syncthreads();
    if (tid < SCAN_NB) bscan[tid] = src[tid] - v;
}

__global__ void k_scan_add(int* __restrict__ off, const int* __restrict__ bscan) {
    int i = blockIdx.x * blockDim.x + threadIdx.x;
    if (i < NTGT) off[i] += bscan[i >> 9];
}

// ---------------- bucket edges by target ----------------
__global__ void k_build(const int* __restrict__ row, const int* __restrict__ col,
                        const int* __restrict__ off, int* __restrict__ cursor,
                        int* __restrict__ csr) {
    int e = blockIdx.x * blockDim.x + threadIdx.x;
    if (e < NEDGE) {
        int c = col[e];
        int pos = off[c] + atomicAdd(&cursor[c], 1);
        csr[pos] = row[e];
    }
}

// ---------------- h = x @ W via bf16 MFMA; h stored bf16; out_s fused -----
// block = 256 thr (4 waves). 64 rows/block. Wave w -> rows base+w*16..+15.
// 8 n-tiles of 16 cols cover N=128; K=128 in 4 MFMA steps of 32.
__global__ __launch_bounds__(256) void k_gemm(const float* __restrict__ xsrc,
                                              const float* __restrict__ xtgt,
                                              const float* __restrict__ W,
                                              unsigned short* __restrict__ h,
                                              float* __restrict__ out) {
    __shared__ unsigned short Wt[128 * 136];  // [n][k] bf16, pad 136: 2-way free
    __shared__ unsigned short Hs[64 * 128];   // staging for coalesced stores

    const int tid = threadIdx.x;

    // stage W transposed -> bf16 (one time)
    for (int idx = tid; idx < 128 * 128; idx += 256) {
        int k = idx >> 7, n = idx & 127;
        Wt[n * 136 + k] = f2bf(W[idx]);
    }
    __syncthreads();

    const int wave = tid >> 6, lane = tid & 63;
    const int nl = lane & 15, quad = lane >> 4;
    const int base = blockIdx.x * 64;

    int m = base + wave * 16 + nl;
    int mc = (m < NTOT) ? m : (NTOT - 1);  // clamp tail loads
    const float* xrow = (mc < NSRC) ? (xsrc + (size_t)mc * DIM)
                                    : (xtgt + (size_t)(mc - NSRC) * DIM);

    float4v acc[8];
#pragma unroll
    for (int t = 0; t < 8; ++t) acc[t] = (float4v){0.f, 0.f, 0.f, 0.f};

#pragma unroll
    for (int s = 0; s < 4; ++s) {
        int k0 = s * 32 + quad * 8;
        float4 a0 = *(const float4*)(xrow + k0);
        float4 a1 = *(const float4*)(xrow + k0 + 4);
        short8 af;
        af[0] = (short)f2bf(a0.x); af[1] = (short)f2bf(a0.y);
        af[2] = (short)f2bf(a0.z); af[3] = (short)f2bf(a0.w);
        af[4] = (short)f2bf(a1.x); af[5] = (short)f2bf(a1.y);
        af[6] = (short)f2bf(a1.z); af[7] = (short)f2bf(a1.w);
#pragma unroll
        for (int t = 0; t < 8; ++t) {
            short8 bf = *(const short8*)&Wt[(t * 16 + nl) * 136 + k0];
            acc[t] = __builtin_amdgcn_mfma_f32_16x16x32_bf16(af, bf, acc[t], 0, 0, 0);
        }
    }

    // C/D layout: col = lane&15 (within n-tile), row = quad*4 + reg
#pragma unroll
    for (int t = 0; t < 8; ++t)
#pragma unroll
        for (int r = 0; r < 4; ++r)
            Hs[(wave * 16 + quad * 4 + r) * 128 + t * 16 + nl] = f2bf(acc[t][r]);
    __syncthreads();

    // coalesced readout: each thread 4 chunks of 8 bf16
#pragma unroll
    for (int j = 0; j < 4; ++j) {
        int off_us = tid * 8 + j * 2048;  // ushort index into Hs
        int g = base + (off_us >> 7);
        int colc = off_us & 127;
        if (g < NTOT) {
            uint4 v = *(const uint4*)&Hs[off_us];
            *(uint4*)(h + (size_t)g * DIM + colc) = v;
            if (g < NSRC) {  // source nodes: deg=1 -> out = relu(h)
                unsigned pk[4] = {v.x, v.y, v.z, v.w};
                float4 o0, o1;
                o0.x = fmaxf(bf2f(pk[0] & 0xffff), 0.f);
                o0.y = fmaxf(bf2f(pk[0] >> 16), 0.f);
                o0.z = fmaxf(bf2f(pk[1] & 0xffff), 0.f);
                o0.w = fmaxf(bf2f(pk[1] >> 16), 0.f);
                o1.x = fmaxf(bf2f(pk[2] & 0xffff), 0.f);
                o1.y = fmaxf(bf2f(pk[2] >> 16), 0.f);
                o1.z = fmaxf(bf2f(pk[3] & 0xffff), 0.f);
                o1.w = fmaxf(bf2f(pk[3] >> 16), 0.f);
                float* op = out + (size_t)g * DIM + colc;
                *(float4*)op = o0;
                *(float4*)(op + 4) = o1;
            }
        }
    }
}

// ---------------- per-target gather-reduce (bf16 h) ----------------
// one wave per target; lane covers 2 cols (1 dword = 2 bf16); 4 targets/block
__global__ __launch_bounds__(256) void k_agg(const int* __restrict__ off,
                                             const int* __restrict__ cnt,
                                             const int* __restrict__ csr,
                                             const unsigned short* __restrict__ h,
                                             float* __restrict__ out) {
    int w = threadIdx.x >> 6;
    int lane = threadIdx.x & 63;
    int c = blockIdx.x * 4 + w;
    if (c >= NTGT) return;

    int s0 = off[c];
    int n = cnt[c];

    float sx = 0.f, sy = 0.f;
    int j = 0;
    while (j < n) {
        int nb = (n - j < 64) ? (n - j) : 64;
        int v = (lane < nb) ? csr[s0 + j + lane] : 0;
#pragma unroll 8
        for (int k = 0; k < nb; ++k) {
            int r = __shfl(v, k, 64);
            unsigned d = *(const unsigned*)(h + (size_t)r * DIM + lane * 2);
            sx += bf2f(d & 0xffff);
            sy += bf2f(d >> 16);
        }
        j += nb;
    }

    float di = rsqrtf(1.0f + (float)n);
    unsigned dh = *(const unsigned*)(h + (size_t)(NSRC + c) * DIM + lane * 2);
    float2 o;
    o.x = fmaxf(di * sx + di * di * bf2f(dh & 0xffff), 0.f);
    o.y = fmaxf(di * sy + di * di * bf2f(dh >> 16), 0.f);
    ((float2*)out)[(size_t)(NSRC + c) * 64 + lane] = o;
}

extern "C" void kernel_launch(void* const* d_in, const int* in_sizes, int n_in,
                              void* d_out, int out_size, void* d_ws, size_t ws_size,
                              hipStream_t stream) {
    const int* ei     = (const int*)d_in[0];    // [2, E] int32
    const float* xsrc = (const float*)d_in[1];  // [NSRC, 128]
    const float* xtgt = (const float*)d_in[2];  // [NTGT, 128]
    const float* W    = (const float*)d_in[3];  // [128, 128]
    float* out = (float*)d_out;                 // [NTOT, 128]

    const int* row = ei;
    const int* col = ei + NEDGE;

    char* ws = (char*)d_ws;
    unsigned short* h = (unsigned short*)ws;  ws += (size_t)NTOT * DIM * 2;  // 25.6 MB
    int* cnt    = (int*)ws;                   ws += NTGT * 4;
    int* cursor = (int*)ws;                   ws += NTGT * 4;
    int* off    = (int*)ws;                   ws += NTGT * 4;
    int* bsum   = (int*)ws;                   ws += 512;
    int* bscan  = (int*)ws;                   ws += 512;
    int* csr    = (int*)ws;                   ws += (size_t)NEDGE * 4;       // 3.2 MB

    k_zero<<<(2 * NTGT + 255) / 256, 256, 0, stream>>>(cnt, 2 * NTGT);  // cnt+cursor
    k_hist<<<(NEDGE + 255) / 256, 256, 0, stream>>>(col, cnt);
    k_scan_block<<<SCAN_NB, SCAN_BLK, 0, stream>>>(cnt, off, bsum);
    k_scan_top<<<1, 128, 0, stream>>>(bsum, bscan);
    k_scan_add<<<(NTGT + 255) / 256, 256, 0, stream>>>(off, bscan);
    k_build<<<(NEDGE + 255) / 256, 256, 0, stream>>>(row, col, off, cursor, csr);
    k_gemm<<<(NTOT + 63) / 64, 256, 0, stream>>>(xsrc, xtgt, W, h, out);
    k_agg<<<(NTGT + 3) / 4, 256, 0, stream>>>(off, cnt, csr, h, out);
}